// Round 1
// baseline (215.042 us; speedup 1.0000x reference)
//
#include <hip/hip_runtime.h>
#include <cstdint>

#define D_MODEL 1024
#define BATCH 4
#define SEQ 4096
#define M_TOT (BATCH*SEQ)   // 16384

#define BM 128
#define BN 64
#define BK 64
#define PAD 8
#define LDK (BK+PAD)        // 72 bf16 elems = 144 B rows (16B aligned)

#define NCHUNK 64
#define CHUNK 64

typedef __bf16 bf16x8 __attribute__((ext_vector_type(8)));
typedef float f32x4 __attribute__((ext_vector_type(4)));
typedef unsigned short u16x8 __attribute__((ext_vector_type(8)));

static __device__ __forceinline__ unsigned short f2bf(float f) {
    unsigned int u = __float_as_uint(f);
    return (unsigned short)((u + 0x7fffu + ((u >> 16) & 1u)) >> 16);
}

// ---------------- convert x (fp32 -> bf16), 8 elems/thread ----------------
__global__ void k_convert_x(const float* __restrict__ x, unsigned short* __restrict__ xb) {
    int i = blockIdx.x * 256 + threadIdx.x;   // 2,097,152 threads
    const float4* p = (const float4*)x;
    float4 v0 = p[2*i], v1 = p[2*i+1];
    u16x8 r;
    r[0] = f2bf(v0.x); r[1] = f2bf(v0.y); r[2] = f2bf(v0.z); r[3] = f2bf(v0.w);
    r[4] = f2bf(v1.x); r[5] = f2bf(v1.y); r[6] = f2bf(v1.z); r[7] = f2bf(v1.w);
    *(u16x8*)(xb + (size_t)i * 8) = r;
}

// ---------------- transpose + convert W: wt[g][n][k] = W_g[k][n] ----------
__global__ void k_transpose_w(const float* __restrict__ Wf, const float* __restrict__ Wi,
                              const float* __restrict__ Wb, unsigned short* __restrict__ wt) {
    __shared__ float tile[32][33];
    int g = blockIdx.z;
    const float* W = (g == 0) ? Wf : (g == 1) ? Wi : Wb;
    int n0 = blockIdx.x * 32, k0 = blockIdx.y * 32;
    int tx = threadIdx.x, ty = threadIdx.y;   // 32 x 8
    for (int j = 0; j < 4; ++j)
        tile[ty + j*8][tx] = W[(size_t)(k0 + ty + j*8) * D_MODEL + n0 + tx];
    __syncthreads();
    for (int j = 0; j < 4; ++j) {
        int n = n0 + ty + j*8;
        wt[(size_t)g * D_MODEL * D_MODEL + (size_t)n * D_MODEL + k0 + tx] = f2bf(tile[tx][ty + j*8]);
    }
}

// ---------------- fused 3-gate GEMM + epilogue ----------------------------
// computes z_g = x @ W_g + bias_g for g in {f,i,b}; writes
//   a  = sigmoid(-z_f)            (fp32)
//   bg = sigmoid(z_i) * z_b/32    (fp32, into d_out as scratch)
__launch_bounds__(512)
__global__ void k_gemm_gates(const unsigned short* __restrict__ xb, const unsigned short* __restrict__ wt,
                             const float* __restrict__ bfv, const float* __restrict__ biv,
                             const float* __restrict__ bbv,
                             float* __restrict__ a_out, float* __restrict__ bg_out) {
    __shared__ unsigned short xs[BM][LDK];
    __shared__ unsigned short wsm[3][BN][LDK];

    const int tid = threadIdx.x;
    const int m0 = blockIdx.x * BM;
    const int n0 = blockIdx.y * BN;
    const int lane = tid & 63;
    const int wave = tid >> 6;            // 0..7
    const int wrow0 = (wave >> 1) * 32;   // 0,32,64,96
    const int wcol0 = (wave & 1) * 32;    // 0,32
    const int lr = lane & 15;
    const int lg = lane >> 4;             // k-group 0..3

    f32x4 acc[3][2][2] = {};

    for (int kt = 0; kt < D_MODEL; kt += BK) {
        // stage x tile: 128 rows x 64 k (bf16), 16B chunks, 2 per thread
        #pragma unroll
        for (int r = 0; r < 2; ++r) {
            int idx = tid + r * 512;
            int row = idx >> 3, c8 = (idx & 7) * 8;
            uint4 v = *(const uint4*)(xb + (size_t)(m0 + row) * D_MODEL + kt + c8);
            *(uint4*)(&xs[row][c8]) = v;
        }
        // stage 3 W tiles: 64 n-rows x 64 k each
        #pragma unroll
        for (int g = 0; g < 3; ++g) {
            int row = tid >> 3, c8 = (tid & 7) * 8;
            uint4 v = *(const uint4*)(wt + (size_t)g * D_MODEL * D_MODEL +
                                      (size_t)(n0 + row) * D_MODEL + kt + c8);
            *(uint4*)(&wsm[g][row][c8]) = v;
        }
        __syncthreads();

        #pragma unroll
        for (int kk = 0; kk < BK; kk += 32) {
            const int klo = kk + lg * 8;
            bf16x8 af[2];
            bf16x8 bfr[3][2];
            #pragma unroll
            for (int mi = 0; mi < 2; ++mi)
                af[mi] = *(const bf16x8*)(&xs[wrow0 + mi*16 + lr][klo]);
            #pragma unroll
            for (int g = 0; g < 3; ++g)
                #pragma unroll
                for (int ni = 0; ni < 2; ++ni)
                    bfr[g][ni] = *(const bf16x8*)(&wsm[g][wcol0 + ni*16 + lr][klo]);
            #pragma unroll
            for (int g = 0; g < 3; ++g)
                #pragma unroll
                for (int mi = 0; mi < 2; ++mi)
                    #pragma unroll
                    for (int ni = 0; ni < 2; ++ni)
                        acc[g][mi][ni] = __builtin_amdgcn_mfma_f32_16x16x32_bf16(
                            af[mi], bfr[g][ni], acc[g][mi][ni], 0, 0, 0);
        }
        __syncthreads();
    }

    // epilogue: C/D layout (m89-verified): col = lane&15, row = (lane>>4)*4 + reg
    #pragma unroll
    for (int mi = 0; mi < 2; ++mi) {
        #pragma unroll
        for (int ni = 0; ni < 2; ++ni) {
            const int col = n0 + wcol0 + ni*16 + lr;
            const float vbf = bfv[col], vbi = biv[col], vbb = bbv[col];
            #pragma unroll
            for (int r = 0; r < 4; ++r) {
                const int row = m0 + wrow0 + mi*16 + lg*4 + r;
                const float zf = acc[0][mi][ni][r] + vbf;
                const float zi = acc[1][mi][ni][r] + vbi;
                const float zb = (acc[2][mi][ni][r] + vbb) * 0.03125f;  // /sqrt(1024)
                const float a  = 1.0f / (1.0f + __expf(zf));    // 1 - sigmoid(zf)
                const float ig = 1.0f / (1.0f + __expf(-zi));
                const size_t o = (size_t)row * D_MODEL + col;
                a_out[o]  = a;
                bg_out[o] = ig * zb;
            }
        }
    }
}

// ---------------- scan pass 1: per-chunk aggregates -----------------------
__global__ void k_chunk_local(const float* __restrict__ a, const float* __restrict__ bg,
                              float* __restrict__ Ac, float* __restrict__ Bc) {
    const int d = (blockIdx.x & 3) * 256 + threadIdx.x;
    const int c = (blockIdx.x >> 2) & 63;
    const int b = blockIdx.x >> 8;
    const size_t base = ((size_t)b * SEQ + (size_t)c * CHUNK) * D_MODEL + d;
    float A = 1.0f, Bv = 0.0f;
    for (int t = 0; t < CHUNK; ++t) {
        const float av = a[base + (size_t)t * D_MODEL];
        const float bv = bg[base + (size_t)t * D_MODEL];
        A *= av;
        Bv = fmaf(av, Bv, bv);
    }
    const size_t o = ((size_t)b * NCHUNK + c) * D_MODEL + d;
    Ac[o] = A;
    Bc[o] = Bv;
}

// ---------------- scan pass 2: exclusive prefix over chunks ---------------
__global__ void k_chunk_prefix(const float* __restrict__ Ac, const float* __restrict__ Bc,
                               float* __restrict__ H) {
    const int d = (blockIdx.x & 3) * 256 + threadIdx.x;
    const int b = blockIdx.x >> 2;
    float h = 0.0f;
    for (int c = 0; c < NCHUNK; ++c) {
        const size_t o = ((size_t)b * NCHUNK + c) * D_MODEL + d;
        H[o] = h;                     // state entering chunk c
        h = fmaf(Ac[o], h, Bc[o]);
    }
}

// ---------------- scan pass 3: apply (io holds bg in, h out) --------------
__global__ void k_apply(const float* __restrict__ a, float* io, const float* __restrict__ H) {
    const int d = (blockIdx.x & 3) * 256 + threadIdx.x;
    const int c = (blockIdx.x >> 2) & 63;
    const int b = blockIdx.x >> 8;
    const size_t base = ((size_t)b * SEQ + (size_t)c * CHUNK) * D_MODEL + d;
    float h = H[((size_t)b * NCHUNK + c) * D_MODEL + d];
    for (int t = 0; t < CHUNK; ++t) {
        const size_t o = base + (size_t)t * D_MODEL;
        const float bv = io[o];       // read bg before overwrite (same thread)
        h = fmaf(a[o], h, bv);
        io[o] = h;
    }
}

extern "C" void kernel_launch(void* const* d_in, const int* in_sizes, int n_in,
                              void* d_out, int out_size, void* d_ws, size_t ws_size,
                              hipStream_t stream) {
    const float* x   = (const float*)d_in[0];
    const float* Wf  = (const float*)d_in[1];
    const float* bfv = (const float*)d_in[2];
    const float* Wi  = (const float*)d_in[3];
    const float* biv = (const float*)d_in[4];
    const float* Wb  = (const float*)d_in[5];
    const float* bbv = (const float*)d_in[6];
    float* out = (float*)d_out;

    char* ws = (char*)d_ws;
    float*          a_buf = (float*)ws;                          // 64 MiB
    unsigned short* xb    = (unsigned short*)(ws + (64ull << 20));  // 32 MiB
    unsigned short* wt    = (unsigned short*)(ws + (96ull << 20));  // 6 MiB
    // after GEMM, xb region is dead -> reuse for scan aggregates (3 MiB)
    float* Ac = (float*)(ws + (64ull << 20));
    float* Bc = (float*)(ws + (65ull << 20));
    float* Hb = (float*)(ws + (66ull << 20));
    float* bg_buf = out;   // d_out doubles as bg scratch; k_apply overwrites in place

    hipLaunchKernelGGL(k_convert_x, dim3((M_TOT * D_MODEL / 8) / 256), dim3(256), 0, stream, x, xb);
    hipLaunchKernelGGL(k_transpose_w, dim3(32, 32, 3), dim3(32, 8), 0, stream, Wf, Wi, Wb, wt);
    hipLaunchKernelGGL(k_gemm_gates, dim3(M_TOT / BM, D_MODEL / BN), dim3(512), 0, stream,
                       xb, wt, bfv, biv, bbv, a_buf, bg_buf);
    hipLaunchKernelGGL(k_chunk_local, dim3(BATCH * NCHUNK * (D_MODEL / 256)), dim3(256), 0, stream,
                       a_buf, bg_buf, Ac, Bc);
    hipLaunchKernelGGL(k_chunk_prefix, dim3(BATCH * (D_MODEL / 256)), dim3(256), 0, stream,
                       Ac, Bc, Hb);
    hipLaunchKernelGGL(k_apply, dim3(BATCH * NCHUNK * (D_MODEL / 256)), dim3(256), 0, stream,
                       a_buf, bg_buf, Hb);
}

// Round 2
// 190.889 us; speedup vs baseline: 1.1265x; 1.1265x over previous
//
#include <hip/hip_runtime.h>
#include <cstdint>

#define D_MODEL 1024
#define BATCH 4
#define SEQ 4096
#define M_TOT (BATCH*SEQ)   // 16384

#define BM 128
#define BN 128
#define BK 64
#define NKT (D_MODEL/BK)    // 16

#define XS_BYTES 16384              // 128 rows x 128 B (64 bf16 k)
#define WG_BYTES 16384              // per gate: 128 n-rows x 128 B
#define TILE_BYTES (XS_BYTES + 3*WG_BYTES)   // 64 KiB
#define SMEM_BYTES (2*TILE_BYTES)            // 128 KiB double-buffered

#define NCHUNK 64
#define CHUNK 64

typedef __bf16 bf16x8 __attribute__((ext_vector_type(8)));
typedef float f32x4 __attribute__((ext_vector_type(4)));
typedef unsigned short u16x8 __attribute__((ext_vector_type(8)));

static __device__ __forceinline__ unsigned short f2bf(float f) {
    unsigned int u = __float_as_uint(f);
    return (unsigned short)((u + 0x7fffu + ((u >> 16) & 1u)) >> 16);
}

// ---------------- convert x (fp32 -> bf16), 8 elems/thread ----------------
__global__ void k_convert_x(const float* __restrict__ x, unsigned short* __restrict__ xb) {
    int i = blockIdx.x * 256 + threadIdx.x;
    const float4* p = (const float4*)x;
    float4 v0 = p[2*i], v1 = p[2*i+1];
    u16x8 r;
    r[0] = f2bf(v0.x); r[1] = f2bf(v0.y); r[2] = f2bf(v0.z); r[3] = f2bf(v0.w);
    r[4] = f2bf(v1.x); r[5] = f2bf(v1.y); r[6] = f2bf(v1.z); r[7] = f2bf(v1.w);
    *(u16x8*)(xb + (size_t)i * 8) = r;
}

// ---------------- transpose + convert W: wt[g][n][k] = W_g[k][n] ----------
__global__ void k_transpose_w(const float* __restrict__ Wf, const float* __restrict__ Wi,
                              const float* __restrict__ Wb, unsigned short* __restrict__ wt) {
    __shared__ float tile[32][33];
    int g = blockIdx.z;
    const float* W = (g == 0) ? Wf : (g == 1) ? Wi : Wb;
    int n0 = blockIdx.x * 32, k0 = blockIdx.y * 32;
    int tx = threadIdx.x, ty = threadIdx.y;   // 32 x 8
    for (int j = 0; j < 4; ++j)
        tile[ty + j*8][tx] = W[(size_t)(k0 + ty + j*8) * D_MODEL + n0 + tx];
    __syncthreads();
    for (int j = 0; j < 4; ++j) {
        int n = n0 + ty + j*8;
        wt[(size_t)g * D_MODEL * D_MODEL + (size_t)n * D_MODEL + k0 + tx] = f2bf(tile[tx][ty + j*8]);
    }
}

// ---------------- fused 3-gate GEMM + epilogue ----------------------------
// global_load_lds staging (linear LDS dest, inverse-swizzled global src);
// ds_read with XOR swizzle byte ^= (row&7)<<4; 2-phase double-buffered loop.
#define GL16(gp, lp) \
    __builtin_amdgcn_global_load_lds((const __attribute__((address_space(1))) void*)(gp), \
                                     (__attribute__((address_space(3))) void*)(lp), 16, 0, 0)

__launch_bounds__(512, 2)
__global__ void k_gemm_gates(const unsigned short* __restrict__ xb, const unsigned short* __restrict__ wt,
                             const float* __restrict__ bfv, const float* __restrict__ biv,
                             const float* __restrict__ bbv,
                             float* __restrict__ a_out, float* __restrict__ bg_out) {
    extern __shared__ char smem[];
    const int tid  = threadIdx.x;
    const int wave = tid >> 6;
    const int lane = tid & 63;
    const int lr = lane & 15, lg = lane >> 4;
    const int m0 = blockIdx.x * BM;
    const int n0 = blockIdx.y * BN;
    const int wrow = (wave >> 2) * 64;    // 0 or 64
    const int wcol = (wave & 3) * 32;     // 0,32,64,96

    // ---- staging source pointers (8 issues x 512 thr x 16B = 64 KiB/tile)
    const int srow = tid >> 3;                                  // 0..63
    const int scb  = ((tid & 7) * 16) ^ ((srow & 7) << 4);      // swizzled byte col
    const unsigned short* s0 = xb + (size_t)(m0 + srow)      * D_MODEL + (scb >> 1);
    const unsigned short* s1 = xb + (size_t)(m0 + 64 + srow) * D_MODEL + (scb >> 1);
    const unsigned short* s2 = wt + 0ull*D_MODEL*D_MODEL + (size_t)(n0 + srow)      * D_MODEL + (scb >> 1);
    const unsigned short* s3 = wt + 0ull*D_MODEL*D_MODEL + (size_t)(n0 + 64 + srow) * D_MODEL + (scb >> 1);
    const unsigned short* s4 = wt + 1ull*D_MODEL*D_MODEL + (size_t)(n0 + srow)      * D_MODEL + (scb >> 1);
    const unsigned short* s5 = wt + 1ull*D_MODEL*D_MODEL + (size_t)(n0 + 64 + srow) * D_MODEL + (scb >> 1);
    const unsigned short* s6 = wt + 2ull*D_MODEL*D_MODEL + (size_t)(n0 + srow)      * D_MODEL + (scb >> 1);
    const unsigned short* s7 = wt + 2ull*D_MODEL*D_MODEL + (size_t)(n0 + 64 + srow) * D_MODEL + (scb >> 1);

#define STAGE(bufsel) do { \
        char* _b = smem + (bufsel)*TILE_BYTES + wave*1024; \
        GL16(s0, _b + 0*8192); GL16(s1, _b + 1*8192); \
        GL16(s2, _b + 2*8192); GL16(s3, _b + 3*8192); \
        GL16(s4, _b + 4*8192); GL16(s5, _b + 5*8192); \
        GL16(s6, _b + 6*8192); GL16(s7, _b + 7*8192); \
        s0 += BK; s1 += BK; s2 += BK; s3 += BK; \
        s4 += BK; s5 += BK; s6 += BK; s7 += BK; \
    } while (0)

    f32x4 acc[3][4][2] = {};
    const int sxor = (lr & 7) << 4;   // read-side swizzle (row&7 == lr&7 for all our rows)

    STAGE(0);
    __syncthreads();

    for (int kt = 0; kt < NKT; ++kt) {
        if (kt + 1 < NKT) STAGE((kt + 1) & 1);

        const char* tb = smem + (kt & 1) * TILE_BYTES;
        #pragma unroll
        for (int kk = 0; kk < 2; ++kk) {
            const int ko = (kk*64 + lg*16) ^ sxor;   // byte offset within 128B row
            bf16x8 af[4];
            bf16x8 bw[3][2];
            #pragma unroll
            for (int mi = 0; mi < 4; ++mi)
                af[mi] = *(const bf16x8*)(tb + (wrow + mi*16 + lr)*128 + ko);
            #pragma unroll
            for (int g = 0; g < 3; ++g)
                #pragma unroll
                for (int ni = 0; ni < 2; ++ni)
                    bw[g][ni] = *(const bf16x8*)(tb + XS_BYTES + g*WG_BYTES +
                                                 (wcol + ni*16 + lr)*128 + ko);
            #pragma unroll
            for (int g = 0; g < 3; ++g)
                #pragma unroll
                for (int mi = 0; mi < 4; ++mi)
                    #pragma unroll
                    for (int ni = 0; ni < 2; ++ni)
                        acc[g][mi][ni] = __builtin_amdgcn_mfma_f32_16x16x32_bf16(
                            af[mi], bw[g][ni], acc[g][mi][ni], 0, 0, 0);
        }
        __syncthreads();
    }

    // epilogue: C/D layout: col = lane&15, row = (lane>>4)*4 + reg
    #pragma unroll
    for (int ni = 0; ni < 2; ++ni) {
        const int col = n0 + wcol + ni*16 + lr;
        const float vbf = bfv[col], vbi = biv[col], vbb = bbv[col];
        #pragma unroll
        for (int mi = 0; mi < 4; ++mi) {
            #pragma unroll
            for (int r = 0; r < 4; ++r) {
                const int row = m0 + wrow + mi*16 + lg*4 + r;
                const float zf = acc[0][mi][ni][r] + vbf;
                const float zi = acc[1][mi][ni][r] + vbi;
                const float zb = (acc[2][mi][ni][r] + vbb) * 0.03125f;  // /sqrt(1024)
                const float a  = 1.0f / (1.0f + __expf(zf));    // 1 - sigmoid(zf)
                const float ig = 1.0f / (1.0f + __expf(-zi));
                const size_t o = (size_t)row * D_MODEL + col;
                a_out[o]  = a;
                bg_out[o] = ig * zb;
            }
        }
    }
#undef STAGE
}

// ---------------- scan pass 1: per-chunk aggregates -----------------------
__global__ void k_chunk_local(const float* __restrict__ a, const float* __restrict__ bg,
                              float* __restrict__ Ac, float* __restrict__ Bc) {
    const int d = (blockIdx.x & 3) * 256 + threadIdx.x;
    const int c = (blockIdx.x >> 2) & 63;
    const int b = blockIdx.x >> 8;
    const size_t base = ((size_t)b * SEQ + (size_t)c * CHUNK) * D_MODEL + d;
    float A = 1.0f, Bv = 0.0f;
    for (int t = 0; t < CHUNK; ++t) {
        const float av = a[base + (size_t)t * D_MODEL];
        const float bv = bg[base + (size_t)t * D_MODEL];
        A *= av;
        Bv = fmaf(av, Bv, bv);
    }
    const size_t o = ((size_t)b * NCHUNK + c) * D_MODEL + d;
    Ac[o] = A;
    Bc[o] = Bv;
}

// ---------------- scan pass 2: exclusive prefix over chunks ---------------
__global__ void k_chunk_prefix(const float* __restrict__ Ac, const float* __restrict__ Bc,
                               float* __restrict__ H) {
    const int d = (blockIdx.x & 3) * 256 + threadIdx.x;
    const int b = blockIdx.x >> 2;
    float h = 0.0f;
    for (int c = 0; c < NCHUNK; ++c) {
        const size_t o = ((size_t)b * NCHUNK + c) * D_MODEL + d;
        H[o] = h;                     // state entering chunk c
        h = fmaf(Ac[o], h, Bc[o]);
    }
}

// ---------------- scan pass 3: apply (io holds bg in, h out) --------------
__global__ void k_apply(const float* __restrict__ a, float* io, const float* __restrict__ H) {
    const int d = (blockIdx.x & 3) * 256 + threadIdx.x;
    const int c = (blockIdx.x >> 2) & 63;
    const int b = blockIdx.x >> 8;
    const size_t base = ((size_t)b * SEQ + (size_t)c * CHUNK) * D_MODEL + d;
    float h = H[((size_t)b * NCHUNK + c) * D_MODEL + d];
    for (int t = 0; t < CHUNK; ++t) {
        const size_t o = base + (size_t)t * D_MODEL;
        const float bv = io[o];       // read bg before overwrite (same thread)
        h = fmaf(a[o], h, bv);
        io[o] = h;
    }
}

extern "C" void kernel_launch(void* const* d_in, const int* in_sizes, int n_in,
                              void* d_out, int out_size, void* d_ws, size_t ws_size,
                              hipStream_t stream) {
    const float* x   = (const float*)d_in[0];
    const float* Wf  = (const float*)d_in[1];
    const float* bfv = (const float*)d_in[2];
    const float* Wi  = (const float*)d_in[3];
    const float* biv = (const float*)d_in[4];
    const float* Wb  = (const float*)d_in[5];
    const float* bbv = (const float*)d_in[6];
    float* out = (float*)d_out;

    char* ws = (char*)d_ws;
    float*          a_buf = (float*)ws;                             // 64 MiB
    unsigned short* xb    = (unsigned short*)(ws + (64ull << 20));  // 32 MiB
    unsigned short* wt    = (unsigned short*)(ws + (96ull << 20));  // 6 MiB
    float* Ac = (float*)(ws + (64ull << 20));   // reuse xb region after GEMM
    float* Bc = (float*)(ws + (65ull << 20));
    float* Hb = (float*)(ws + (66ull << 20));
    float* bg_buf = out;   // d_out doubles as bg scratch; k_apply overwrites in place

    static int smem_set = 0;
    if (!smem_set) {
        hipFuncSetAttribute((const void*)k_gemm_gates,
                            hipFuncAttributeMaxDynamicSharedMemorySize, SMEM_BYTES);
        smem_set = 1;
    }

    hipLaunchKernelGGL(k_convert_x, dim3((M_TOT * D_MODEL / 8) / 256), dim3(256), 0, stream, x, xb);
    hipLaunchKernelGGL(k_transpose_w, dim3(32, 32, 3), dim3(32, 8), 0, stream, Wf, Wi, Wb, wt);
    hipLaunchKernelGGL(k_gemm_gates, dim3(M_TOT / BM, D_MODEL / BN), dim3(512), SMEM_BYTES, stream,
                       xb, wt, bfv, biv, bbv, a_buf, bg_buf);
    hipLaunchKernelGGL(k_chunk_local, dim3(BATCH * NCHUNK * (D_MODEL / 256)), dim3(256), 0, stream,
                       a_buf, bg_buf, Ac, Bc);
    hipLaunchKernelGGL(k_chunk_prefix, dim3(BATCH * (D_MODEL / 256)), dim3(256), 0, stream,
                       Ac, Bc, Hb);
    hipLaunchKernelGGL(k_apply, dim3(BATCH * NCHUNK * (D_MODEL / 256)), dim3(256), 0, stream,
                       a_buf, bg_buf, Hb);
}